// Round 4
// baseline (176.348 us; speedup 1.0000x reference)
//
#include <hip/hip_runtime.h>
#include <hip/hip_bf16.h>

typedef __bf16 bf16;
typedef __bf16 bf16x2 __attribute__((ext_vector_type(2)));
typedef __bf16 bf16x8 __attribute__((ext_vector_type(8)));
typedef float f32x4 __attribute__((ext_vector_type(4)));
typedef int i32x4 __attribute__((ext_vector_type(4)));

#define B_ 8
#define N_ 1024
#define C_ 256
#define H_ 8
#define C3_ 768
#define SCALE 0.17677669529663689f  // 1/sqrt(32), pre-folded into q
#define FMAX 16.0f                  // fixed softmax max, pre-folded into ebtl

// ws layout:
//   Wq_tiled [8 kt][12 nt][64 n][32 k]   393216 B  @ 0
//   Wp_tiled [8 kt][256 n][32 k]         131072 B  @ 393216
//   q  [8192][256] (pre-scaled by SCALE) 4 MiB     @ 524288
//   kT [b][h][1024 n][32 d]              4 MiB     @ 4718592
//   vT [b][c=h*32+d][1024 n']            4 MiB     @ 8912896
// NEW perm (matches swapped-QK P fragment, k-slot = quad*8+e):
//   n' = (n&~31) | ((n&12)<<1) | (n&3) | (((n>>4)&1)<<2)

// ---------------------------------------------------------------------------
// prep: transpose + convert weights into tiled bf16 layouts (one-off, tiny).
// ---------------------------------------------------------------------------
__global__ __launch_bounds__(256) void prep(
    const float* __restrict__ Wqkv, const float* __restrict__ Wproj,
    bf16* __restrict__ Wq_tiled, bf16* __restrict__ Wp_tiled)
{
  int bb = blockIdx.x;
  int o = bb * 256 + threadIdx.x;
  if (bb < 768) {
    int kk = o & 31;
    int idx = o >> 5;
    int nr = idx & 63;
    int qq = idx >> 6;            // kt*12 + nt
    int nt = qq % 12, kt = qq / 12;
    int n = nt * 64 + nr, k = kt * 32 + kk;
    Wq_tiled[o] = (bf16)Wqkv[k * C3_ + n];
  } else {
    int p = o - 768 * 256;
    int kk = p & 31;
    int n = (p >> 5) & 255;
    int kt = p >> 13;
    int k = kt * 32 + kk;
    Wp_tiled[p] = (bf16)Wproj[k * C_ + n];
  }
}

// ---------------------------------------------------------------------------
// QKV projection, 128x128 block tile (m93-class): 4 waves, each 64x64 via
// 4x4 f32x4 accumulators -> 16 MFMA per 8 ds_read_b128 per k-step.
// ---------------------------------------------------------------------------
__global__ __launch_bounds__(256) void gemm_qkv(
    const float* __restrict__ A, const bf16* __restrict__ Wq_tiled,
    bf16* __restrict__ q, bf16* __restrict__ kT, bf16* __restrict__ vT)
{
  __shared__ bf16 As[128][40];
  __shared__ bf16 Bts[128][40];   // Bts[n][k]
  __shared__ bf16 Vls[64][136];   // v-epilogue transpose buffer (64ch x 128n)

  int tid = threadIdx.x;
  int wave = tid >> 6, lane = tid & 63, quad = lane >> 4, l16 = lane & 15;
  int m0 = blockIdx.x * 128, n0 = blockIdx.y * 128;
  int msub = (wave & 1) * 64, nsub = (wave >> 1) * 64;

  f32x4 acc[4][4] = {};

  int arow = tid >> 1, akc = (tid & 1) * 16;
  const float* aptr = A + (long)(m0 + arow) * C_ + akc;   // + k0
  int bn = tid >> 1, bkc = (tid & 1) * 16;
  const bf16* bptr = Wq_tiled +
      ((long)(blockIdx.y * 2 + (bn >> 6)) * 2048 + (bn & 63) * 32 + bkc);

  float4 a0 = *reinterpret_cast<const float4*>(aptr);
  float4 a1 = *reinterpret_cast<const float4*>(aptr + 4);
  float4 a2 = *reinterpret_cast<const float4*>(aptr + 8);
  float4 a3 = *reinterpret_cast<const float4*>(aptr + 12);
  i32x4 bv0 = *reinterpret_cast<const i32x4*>(bptr);
  i32x4 bv1 = *reinterpret_cast<const i32x4*>(bptr + 8);

  for (int kt = 0; kt < 8; ++kt) {
    __syncthreads();
    {
      bf16 at[16] = {(bf16)a0.x, (bf16)a0.y, (bf16)a0.z, (bf16)a0.w,
                     (bf16)a1.x, (bf16)a1.y, (bf16)a1.z, (bf16)a1.w,
                     (bf16)a2.x, (bf16)a2.y, (bf16)a2.z, (bf16)a2.w,
                     (bf16)a3.x, (bf16)a3.y, (bf16)a3.z, (bf16)a3.w};
      *reinterpret_cast<bf16x8*>(&As[arow][akc]) = *reinterpret_cast<bf16x8*>(at);
      *reinterpret_cast<bf16x8*>(&As[arow][akc + 8]) = *reinterpret_cast<bf16x8*>(at + 8);
      *reinterpret_cast<i32x4*>(&Bts[bn][bkc]) = bv0;
      *reinterpret_cast<i32x4*>(&Bts[bn][bkc + 8]) = bv1;
    }
    __syncthreads();

    if (kt < 7) {
      int kn = (kt + 1) * 32;
      a0 = *reinterpret_cast<const float4*>(aptr + kn);
      a1 = *reinterpret_cast<const float4*>(aptr + kn + 4);
      a2 = *reinterpret_cast<const float4*>(aptr + kn + 8);
      a3 = *reinterpret_cast<const float4*>(aptr + kn + 12);
      bv0 = *reinterpret_cast<const i32x4*>(bptr + (long)(kt + 1) * 24576);
      bv1 = *reinterpret_cast<const i32x4*>(bptr + (long)(kt + 1) * 24576 + 8);
    }

    bf16x8 af[4], bfr[4];
#pragma unroll
    for (int mi = 0; mi < 4; ++mi)
      af[mi] = *reinterpret_cast<const bf16x8*>(&As[msub + mi * 16 + l16][quad * 8]);
#pragma unroll
    for (int ni = 0; ni < 4; ++ni)
      bfr[ni] = *reinterpret_cast<const bf16x8*>(&Bts[nsub + ni * 16 + l16][quad * 8]);
#pragma unroll
    for (int mi = 0; mi < 4; ++mi)
#pragma unroll
      for (int ni = 0; ni < 4; ++ni)
        acc[mi][ni] = __builtin_amdgcn_mfma_f32_16x16x32_bf16(af[mi], bfr[ni], acc[mi][ni], 0, 0, 0);
  }

  if (n0 < 256) {
#pragma unroll
    for (int mi = 0; mi < 4; ++mi)
#pragma unroll
      for (int ni = 0; ni < 4; ++ni)
#pragma unroll
        for (int r = 0; r < 4; ++r) {
          int row = m0 + msub + mi * 16 + quad * 4 + r;
          int col = n0 + nsub + ni * 16 + l16;
          q[(long)row * 256 + col] = (bf16)(acc[mi][ni][r] * SCALE);
        }
  } else if (n0 < 512) {
#pragma unroll
    for (int mi = 0; mi < 4; ++mi)
#pragma unroll
      for (int ni = 0; ni < 4; ++ni)
#pragma unroll
        for (int r = 0; r < 4; ++r) {
          int row = m0 + msub + mi * 16 + quad * 4 + r;
          int c = n0 + nsub + ni * 16 + l16 - 256;
          int b = row >> 10, n = row & 1023;
          int h = c >> 5, d = c & 31;
          kT[(((long)(b * H_ + h)) * N_ + n) * 32 + d] = (bf16)acc[mi][ni][r];
        }
  } else {
    int b = m0 >> 10;
#pragma unroll
    for (int ch = 0; ch < 2; ++ch) {
      __syncthreads();
      if ((nsub >> 6) == ch) {
#pragma unroll
        for (int mi = 0; mi < 4; ++mi)
#pragma unroll
          for (int ni = 0; ni < 4; ++ni)
#pragma unroll
            for (int r = 0; r < 4; ++r) {
              int cc = ni * 16 + l16;                  // 0..63 within half
              int nn = msub + mi * 16 + quad * 4 + r;  // 0..127
              // swapped-QK PV fragment perm: k-slot = 8*((nn&15)>>2) + (nn&3) + 4*((nn>>4)&1)
              int np = (nn & 96) | ((nn & 12) << 1) | (nn & 3) | (((nn >> 4) & 1) << 2);
              Vls[cc][np] = (bf16)acc[mi][ni][r];
            }
      }
      __syncthreads();
      int cc = tid >> 2, nseg = (tid & 3) * 32;
      long base = ((long)(b * C_ + (n0 - 512) + ch * 64 + cc)) * N_ + (m0 & 1023) + nseg;
#pragma unroll
      for (int j = 0; j < 4; ++j)
        *reinterpret_cast<i32x4*>(vT + base + j * 8) =
            *reinterpret_cast<const i32x4*>(&Vls[cc][nseg + j * 8]);
    }
  }
}

// ---------------------------------------------------------------------------
// Flash attention + fused projection — SWAPPED-QK, register-only softmax.
// s = mfma(K, Q) puts P[q=l16][j in {4quad..4quad+3, 16+4quad..+3}] lane-local:
// exactly a PV A-fragment (k-slot quad*8+e <-> j), so P never touches LDS.
// rel is loaded per-lane as one dwordx4 (rows i0+l16, 4 consecutive j).
// Bias gather runs PARALLEL to exp: p = exp(s) * ebtl[rv] (ebtl = exp(bias
// + mask - FMAX); masked entries underflow to exact 0). V read direct from
// vT (new perm). j-loop: no barriers, no staging, double-buffered K/V/rel,
// rel loaded 2 half-tiles before its gather, gather 1 half-tile before use.
// ---------------------------------------------------------------------------
__global__ __launch_bounds__(512) void flash_attn(
    const bf16* __restrict__ q, const bf16* __restrict__ kT,
    const bf16* __restrict__ vT, const int* __restrict__ rel,
    const int* __restrict__ rel_len, const float* __restrict__ btab,
    const bf16* __restrict__ Wp_tiled, const float* __restrict__ bias,
    float* __restrict__ out)
{
  __shared__ float ebtl[H_][16];    // exp(bias + mask - FMAX)
  __shared__ bf16 attL[16][264];    // normalized att rows (all 256 channels)

  int tid = threadIdx.x;
  int h = tid >> 6, lane = tid & 63, quad = lane >> 4, l16 = lane & 15;

  // bijective XCD swizzle (512 blocks = 8 XCDs x 64): XCD k -> batch k
  // (verified R2/R3: FETCH 53.8 -> 23.7 MB).
  int wg = blockIdx.y * 64 + blockIdx.x;
  int swz = (wg & 7) * 64 + (wg >> 3);
  int b = swz >> 6, i0 = (swz & 63) * 16;
  long bN = (long)b * N_;

  int mask_len = (int)((float)rel_len[b] * 0.5f);
  if (tid < 80) {
    int t = tid >> 3, hh = tid & 7;
    ebtl[hh][t] = __expf(btab[t * H_ + hh] + (t > mask_len ? -100.f : 0.f) - FMAX);
  }
  __syncthreads();  // ebtl ready (only barrier before the tail)

  // Q as B-fragment: col = q-row (l16), k = d (quad*8+e)
  bf16x8 qf = *reinterpret_cast<const bf16x8*>(
      q + (bN + i0 + l16) * 256 + h * 32 + quad * 8);

  const bf16* kb_ = kT + ((long)(b * H_ + h)) * N_ * 32 + quad * 8;     // + (j+row)*32
  const bf16* vb_ = vT + ((long)b * C_ + h * 32 + l16) * N_ + quad * 8; // + j (+16*N_ row)
  const int*  rb_ = rel + (bN + i0 + l16) * N_ + quad * 4;              // + j (+16)

  f32x4 oacc[2] = {};
  float l_acc = 0.f;

#define W_(J) ((J) < N_ ? (J) : 0)

#define LD_KV(K0, K1, V0, V1, J) do {                                        \
    K0 = *reinterpret_cast<const bf16x8*>(kb_ + (long)((J) + l16) * 32);     \
    K1 = *reinterpret_cast<const bf16x8*>(kb_ + (long)((J) + 16 + l16) * 32);\
    V0 = *reinterpret_cast<const bf16x8*>(vb_ + (J));                        \
    V1 = *reinterpret_cast<const bf16x8*>(vb_ + 16 * N_ + (J));              \
  } while (0)

#define LD_R(R0, R1, J) do {                                                 \
    R0 = *reinterpret_cast<const i32x4*>(rb_ + (J));                         \
    R1 = *reinterpret_cast<const i32x4*>(rb_ + (J) + 16);                    \
  } while (0)

#define GATH(G, R0, R1) do {                                                 \
    _Pragma("unroll")                                                        \
    for (int e = 0; e < 4; ++e) {                                            \
      G[e]     = ebtl[h][R0[e]];                                             \
      G[4 + e] = ebtl[h][R1[e]];                                             \
    }                                                                        \
  } while (0)

  // COMP: s[j-local][q] = K·Q^T; p = exp(s)*g; pa is directly the PV A-frag.
#define COMP(K0, K1, V0, V1, G) do {                                         \
    f32x4 z = {};                                                            \
    f32x4 s0 = __builtin_amdgcn_mfma_f32_16x16x32_bf16(K0, qf, z, 0, 0, 0);  \
    f32x4 s1 = __builtin_amdgcn_mfma_f32_16x16x32_bf16(K1, qf, z, 0, 0, 0);  \
    bf16x8 pa;                                                               \
    _Pragma("unroll")                                                        \
    for (int e = 0; e < 4; ++e) {                                            \
      float p0 = __expf(s0[e]) * G[e];                                       \
      float p1 = __expf(s1[e]) * G[4 + e];                                   \
      l_acc += p0 + p1;                                                      \
      pa[e] = (bf16)p0;                                                      \
      pa[4 + e] = (bf16)p1;                                                  \
    }                                                                        \
    oacc[0] = __builtin_amdgcn_mfma_f32_16x16x32_bf16(pa, V0, oacc[0], 0, 0, 0); \
    oacc[1] = __builtin_amdgcn_mfma_f32_16x16x32_bf16(pa, V1, oacc[1], 0, 0, 0); \
  } while (0)

  bf16x8 kX0, kX1, vX0, vX1, kY0, kY1, vY0, vY1;
  i32x4 rX0, rX1, rY0, rY1;
  float gX[8], gY[8];

  // prologue: X <- tile 0, Y <- tile 1; gather gX (one-time stall on rel(0)).
  LD_KV(kX0, kX1, vX0, vX1, 0);  LD_R(rX0, rX1, 0);
  LD_KV(kY0, kY1, vY0, vY1, 32); LD_R(rY0, rY1, 32);
  GATH(gX, rX0, rX1);

#pragma unroll 1
  for (int j0 = 0; j0 < N_; j0 += 64) {
    // slot X (tile j0): gather for Y (rel loaded 1 slot ago), compute X,
    // refill X for j0+64 (K,V,rel; its gather happens next slot).
    GATH(gY, rY0, rY1);
    COMP(kX0, kX1, vX0, vX1, gX);
    LD_KV(kX0, kX1, vX0, vX1, W_(j0 + 64));
    LD_R(rX0, rX1, W_(j0 + 64));
    // slot Y (tile j0+32)
    GATH(gX, rX0, rX1);
    COMP(kY0, kY1, vY0, vY1, gY);
    LD_KV(kY0, kY1, vY0, vY1, W_(j0 + 96));
    LD_R(rY0, rY1, W_(j0 + 96));
  }
#undef COMP
#undef GATH
#undef LD_R
#undef LD_KV
#undef W_

  // row sums: lane's 8 p's are all for q-row l16 -> reduce across quads.
  float lsum = l_acc;
  lsum += __shfl_xor(lsum, 16);
  lsum += __shfl_xor(lsum, 32);
  float inv = 1.f / lsum;   // inv for q-row = l16

  // oacc rows are q = quad*4+r -> fetch that row's inv via shuffle.
#pragma unroll
  for (int r = 0; r < 4; ++r) {
    float invr = __shfl(inv, quad * 4 + r);
    attL[quad * 4 + r][h * 32 + l16] = (bf16)(oacc[0][r] * invr);
    attL[quad * 4 + r][h * 32 + 16 + l16] = (bf16)(oacc[1][r] * invr);
  }
  __syncthreads();

  // fused projection: wave h computes out[16 rows][h*32 .. h*32+31]
  f32x4 pacc[2] = {};
  const bf16* wp = Wp_tiled + ((h * 32 + l16) * 32 + quad * 8);  // + kt*8192, +512 for ni=1
#pragma unroll
  for (int kt = 0; kt < 8; ++kt) {
    bf16x8 afr = *reinterpret_cast<const bf16x8*>(&attL[l16][kt * 32 + quad * 8]);
    bf16x8 b0 = *reinterpret_cast<const bf16x8*>(wp + kt * 8192);
    bf16x8 b1 = *reinterpret_cast<const bf16x8*>(wp + kt * 8192 + 512);
    pacc[0] = __builtin_amdgcn_mfma_f32_16x16x32_bf16(afr, b0, pacc[0], 0, 0, 0);
    pacc[1] = __builtin_amdgcn_mfma_f32_16x16x32_bf16(afr, b1, pacc[1], 0, 0, 0);
  }
  float bi0 = bias[h * 32 + l16];
  float bi1 = bias[h * 32 + 16 + l16];
#pragma unroll
  for (int r = 0; r < 4; ++r) {
    long rowoff = (bN + i0 + quad * 4 + r) * C_ + h * 32;
    out[rowoff + l16] = pacc[0][r] + bi0;
    out[rowoff + 16 + l16] = pacc[1][r] + bi1;
  }
}

// ---------------------------------------------------------------------------
extern "C" void kernel_launch(void* const* d_in, const int* in_sizes, int n_in,
                              void* d_out, int out_size, void* d_ws, size_t ws_size,
                              hipStream_t stream) {
  const float* X     = (const float*)d_in[0];   // att_embedding [8,1024,256] fp32
  const int*   rel   = (const int*)d_in[1];     // relation_position [8,1024,1024]
  const int*   rlen  = (const int*)d_in[2];     // rel_len [8]
  const float* Wqkv  = (const float*)d_in[3];   // [256,768] fp32
  const float* Wproj = (const float*)d_in[4];   // [256,256] fp32
  const float* bproj = (const float*)d_in[5];   // [256] fp32
  const float* btab  = (const float*)d_in[6];   // [10,8] fp32
  float* out = (float*)d_out;                   // [8,1024,256] fp32

  char* ws = (char*)d_ws;
  bf16* Wq_tiled = (bf16*)ws;                            // 393216 B
  bf16* Wp_tiled = (bf16*)(ws + 393216);                 // 131072 B
  bf16* q  = (bf16*)(ws + 524288);                       // 4 MiB
  bf16* kT = (bf16*)(ws + 524288 + 4194304);             // 4 MiB
  bf16* vT = (bf16*)(ws + 524288 + 2 * 4194304);         // 4 MiB

  prep<<<dim3(1024), 256, 0, stream>>>(Wqkv, Wproj, Wq_tiled, Wp_tiled);
  gemm_qkv<<<dim3(8192 / 128, C3_ / 128), 256, 0, stream>>>(X, Wq_tiled, q, kT, vT);
  flash_attn<<<dim3(N_ / 16, B_), 512, 0, stream>>>(
      q, kT, vT, rel, rlen, btab, Wp_tiled, bproj, out);
}

// Round 5
// 136.670 us; speedup vs baseline: 1.2903x; 1.2903x over previous
//
#include <hip/hip_runtime.h>
#include <hip/hip_bf16.h>

typedef __bf16 bf16;
typedef __bf16 bf16x2 __attribute__((ext_vector_type(2)));
typedef __bf16 bf16x8 __attribute__((ext_vector_type(8)));
typedef float f32x4 __attribute__((ext_vector_type(4)));
typedef int i32x4 __attribute__((ext_vector_type(4)));

#define B_ 8
#define N_ 1024
#define C_ 256
#define H_ 8
#define C3_ 768
#define SCALE 0.17677669529663689f  // 1/sqrt(32), pre-folded into q
#define FMAX 16.0f                  // fixed softmax max, pre-folded into ebtl

// ws layout:
//   Wq_tiled [8 kt][12 nt][64 n][32 k]   393216 B  @ 0
//   Wp_tiled [8 kt][256 n][32 k]         131072 B  @ 393216
//   q  [8192][256] (pre-scaled by SCALE) 4 MiB     @ 524288
//   kT [b][h][1024 n][32 d]              4 MiB     @ 4718592
//   vT [b][c=h*32+d][1024 n']            4 MiB     @ 8912896
// vT perm (matches swapped-QK P fragment, k-slot = quad*8+e):
//   n' = (n&~31) | ((n&12)<<1) | (n&3) | (((n>>4)&1)<<2)

// ---------------------------------------------------------------------------
// prep: transpose + convert weights into tiled bf16 layouts (one-off, tiny).
// ---------------------------------------------------------------------------
__global__ __launch_bounds__(256) void prep(
    const float* __restrict__ Wqkv, const float* __restrict__ Wproj,
    bf16* __restrict__ Wq_tiled, bf16* __restrict__ Wp_tiled)
{
  int bb = blockIdx.x;
  int o = bb * 256 + threadIdx.x;
  if (bb < 768) {
    int kk = o & 31;
    int idx = o >> 5;
    int nr = idx & 63;
    int qq = idx >> 6;            // kt*12 + nt
    int nt = qq % 12, kt = qq / 12;
    int n = nt * 64 + nr, k = kt * 32 + kk;
    Wq_tiled[o] = (bf16)Wqkv[k * C3_ + n];
  } else {
    int p = o - 768 * 256;
    int kk = p & 31;
    int n = (p >> 5) & 255;
    int kt = p >> 13;
    int k = kt * 32 + kk;
    Wp_tiled[p] = (bf16)Wproj[k * C_ + n];
  }
}

// ---------------------------------------------------------------------------
// QKV projection, 128x128 block tile (m93-class): 4 waves, each 64x64 via
// 4x4 f32x4 accumulators -> 16 MFMA per 8 ds_read_b128 per k-step.
// ---------------------------------------------------------------------------
__global__ __launch_bounds__(256) void gemm_qkv(
    const float* __restrict__ A, const bf16* __restrict__ Wq_tiled,
    bf16* __restrict__ q, bf16* __restrict__ kT, bf16* __restrict__ vT)
{
  __shared__ bf16 As[128][40];
  __shared__ bf16 Bts[128][40];   // Bts[n][k]
  __shared__ bf16 Vls[64][136];   // v-epilogue transpose buffer (64ch x 128n)

  int tid = threadIdx.x;
  int wave = tid >> 6, lane = tid & 63, quad = lane >> 4, l16 = lane & 15;
  int m0 = blockIdx.x * 128, n0 = blockIdx.y * 128;
  int msub = (wave & 1) * 64, nsub = (wave >> 1) * 64;

  f32x4 acc[4][4] = {};

  int arow = tid >> 1, akc = (tid & 1) * 16;
  const float* aptr = A + (long)(m0 + arow) * C_ + akc;   // + k0
  int bn = tid >> 1, bkc = (tid & 1) * 16;
  const bf16* bptr = Wq_tiled +
      ((long)(blockIdx.y * 2 + (bn >> 6)) * 2048 + (bn & 63) * 32 + bkc);

  float4 a0 = *reinterpret_cast<const float4*>(aptr);
  float4 a1 = *reinterpret_cast<const float4*>(aptr + 4);
  float4 a2 = *reinterpret_cast<const float4*>(aptr + 8);
  float4 a3 = *reinterpret_cast<const float4*>(aptr + 12);
  i32x4 bv0 = *reinterpret_cast<const i32x4*>(bptr);
  i32x4 bv1 = *reinterpret_cast<const i32x4*>(bptr + 8);

  for (int kt = 0; kt < 8; ++kt) {
    __syncthreads();
    {
      bf16 at[16] = {(bf16)a0.x, (bf16)a0.y, (bf16)a0.z, (bf16)a0.w,
                     (bf16)a1.x, (bf16)a1.y, (bf16)a1.z, (bf16)a1.w,
                     (bf16)a2.x, (bf16)a2.y, (bf16)a2.z, (bf16)a2.w,
                     (bf16)a3.x, (bf16)a3.y, (bf16)a3.z, (bf16)a3.w};
      *reinterpret_cast<bf16x8*>(&As[arow][akc]) = *reinterpret_cast<bf16x8*>(at);
      *reinterpret_cast<bf16x8*>(&As[arow][akc + 8]) = *reinterpret_cast<bf16x8*>(at + 8);
      *reinterpret_cast<i32x4*>(&Bts[bn][bkc]) = bv0;
      *reinterpret_cast<i32x4*>(&Bts[bn][bkc + 8]) = bv1;
    }
    __syncthreads();

    if (kt < 7) {
      int kn = (kt + 1) * 32;
      a0 = *reinterpret_cast<const float4*>(aptr + kn);
      a1 = *reinterpret_cast<const float4*>(aptr + kn + 4);
      a2 = *reinterpret_cast<const float4*>(aptr + kn + 8);
      a3 = *reinterpret_cast<const float4*>(aptr + kn + 12);
      bv0 = *reinterpret_cast<const i32x4*>(bptr + (long)(kt + 1) * 24576);
      bv1 = *reinterpret_cast<const i32x4*>(bptr + (long)(kt + 1) * 24576 + 8);
    }

    bf16x8 af[4], bfr[4];
#pragma unroll
    for (int mi = 0; mi < 4; ++mi)
      af[mi] = *reinterpret_cast<const bf16x8*>(&As[msub + mi * 16 + l16][quad * 8]);
#pragma unroll
    for (int ni = 0; ni < 4; ++ni)
      bfr[ni] = *reinterpret_cast<const bf16x8*>(&Bts[nsub + ni * 16 + l16][quad * 8]);
#pragma unroll
    for (int mi = 0; mi < 4; ++mi)
#pragma unroll
      for (int ni = 0; ni < 4; ++ni)
        acc[mi][ni] = __builtin_amdgcn_mfma_f32_16x16x32_bf16(af[mi], bfr[ni], acc[mi][ni], 0, 0, 0);
  }

  if (n0 < 256) {
#pragma unroll
    for (int mi = 0; mi < 4; ++mi)
#pragma unroll
      for (int ni = 0; ni < 4; ++ni)
#pragma unroll
        for (int r = 0; r < 4; ++r) {
          int row = m0 + msub + mi * 16 + quad * 4 + r;
          int col = n0 + nsub + ni * 16 + l16;
          q[(long)row * 256 + col] = (bf16)(acc[mi][ni][r] * SCALE);
        }
  } else if (n0 < 512) {
#pragma unroll
    for (int mi = 0; mi < 4; ++mi)
#pragma unroll
      for (int ni = 0; ni < 4; ++ni)
#pragma unroll
        for (int r = 0; r < 4; ++r) {
          int row = m0 + msub + mi * 16 + quad * 4 + r;
          int c = n0 + nsub + ni * 16 + l16 - 256;
          int b = row >> 10, n = row & 1023;
          int h = c >> 5, d = c & 31;
          kT[(((long)(b * H_ + h)) * N_ + n) * 32 + d] = (bf16)acc[mi][ni][r];
        }
  } else {
    int b = m0 >> 10;
#pragma unroll
    for (int ch = 0; ch < 2; ++ch) {
      __syncthreads();
      if ((nsub >> 6) == ch) {
#pragma unroll
        for (int mi = 0; mi < 4; ++mi)
#pragma unroll
          for (int ni = 0; ni < 4; ++ni)
#pragma unroll
            for (int r = 0; r < 4; ++r) {
              int cc = ni * 16 + l16;                  // 0..63 within half
              int nn = msub + mi * 16 + quad * 4 + r;  // 0..127
              // swapped-QK PV fragment perm
              int np = (nn & 96) | ((nn & 12) << 1) | (nn & 3) | (((nn >> 4) & 1) << 2);
              Vls[cc][np] = (bf16)acc[mi][ni][r];
            }
      }
      __syncthreads();
      int cc = tid >> 2, nseg = (tid & 3) * 32;
      long base = ((long)(b * C_ + (n0 - 512) + ch * 64 + cc)) * N_ + (m0 & 1023) + nseg;
#pragma unroll
      for (int j = 0; j < 4; ++j)
        *reinterpret_cast<i32x4*>(vT + base + j * 8) =
            *reinterpret_cast<const i32x4*>(&Vls[cc][nseg + j * 8]);
    }
  }
}

// ---------------------------------------------------------------------------
// Flash attention + fused projection — swapped-QK register softmax, with
// ALL streams (K,V,rel) staged via global_load_lds DMA (sink-proof: no dest
// regs) and COUNTED vmcnt waits (never 0 in the loop). Per tile:
//   issue KV(t+1)+rel(t+3) DMA -> vmcnt(6) -> s_barrier -> ds_reads+compute
//   -> s_barrier. Both barriers raw (no drains). KV double-buffered (1 tile
// of flight), rel quad-buffered (2-3 tiles of flight, covers L3 latency).
// XOR-slot swizzles pre-applied on DMA *global source* (LDS stays linear for
// the DMA); reads un-swizzle -> all ds_read_b128 are 2-way (free).
// ---------------------------------------------------------------------------
__global__ __launch_bounds__(512) void flash_attn(
    const bf16* __restrict__ q, const bf16* __restrict__ kT,
    const bf16* __restrict__ vT, const int* __restrict__ rel,
    const int* __restrict__ rel_len, const float* __restrict__ btab,
    const bf16* __restrict__ Wp_tiled, const float* __restrict__ bias,
    float* __restrict__ out)
{
  // smem map: K [2][8][2048] @0 (32768) | V [2][8][2048] @32768 (32768)
  //           rel [4][2048] @65536 (8192) | ebtl [8][16] f32 @73728 (512)
  // attL [16][264] bf16 aliases @0 after the j-loop (vmcnt(0)+sync first).
  __shared__ __align__(16) char smem[74240];
  char* KBp = smem;
  char* VBp = smem + 32768;
  char* RBp = smem + 65536;
  float* ebtl = (float*)(smem + 73728);

  int tid = threadIdx.x;
  int h = tid >> 6, lane = tid & 63, quad = lane >> 4, l16 = lane & 15;

  // bijective XCD swizzle (512 blocks = 8 XCDs x 64): XCD k -> batch k
  // (verified: FETCH 53.8 -> 23.7 MB).
  int wg = blockIdx.y * 64 + blockIdx.x;
  int swz = (wg & 7) * 64 + (wg >> 3);
  int b = swz >> 6, i0 = (swz & 63) * 16;
  long bN = (long)b * N_;

  int mask_len = (int)((float)rel_len[b] * 0.5f);
  if (tid < 80) {
    int t = tid >> 3, hh = tid & 7;
    ebtl[hh * 16 + t] = __expf(btab[t * H_ + hh] + (t > mask_len ? -100.f : 0.f) - FMAX);
  }

  // Q as B-fragment: col = q-row (l16), k = d (quad*8+e)
  bf16x8 qf = *reinterpret_cast<const bf16x8*>(
      q + (bN + i0 + l16) * 256 + h * 32 + quad * 8);

  // ---- per-lane DMA source offsets (swizzle pre-applied on global addr) ----
  int l = lane;
  int sxc = (((l & 3) ^ ((l >> 3) & 3)) << 4);        // K/V 16B-slot swizzle
  int kc0 = (l >> 2) * 64 + sxc;                      // K DMA i=0; i=1: +1024
  int vc0 = (h * 32 + (l >> 2)) * 2048 + sxc;         // V DMA i=0; i=1: +32768
  int i_loc = (h & 3) * 4 + (l >> 4);
  int j_loc = (h >> 2) * 16 + ((((l >> 2) & 3) ^ ((i_loc >> 1) & 3)) << 2) + (l & 3);
  int rc = i_loc * 4096 + j_loc * 4;                  // rel DMA (size=4)

  const char* kTb = (const char*)kT + ((long)(b * 8 + h) << 16);  // +t*2048
  const char* vTb = (const char*)vT + (long)b * 524288;           // +t*64
  const char* rb0 = (const char*)rel + (bN + i0) * 4096;          // +t*128

  // ---- LDS read offsets (un-swizzle) ----
  int swq = ((quad ^ ((l16 >> 1) & 3)) << 4);
  int kr = h * 2048 + l16 * 64 + swq;   // K/V read (row l16; +1024 row 16+l16)
  int rr = l16 * 64 + swq;              // rel read (jh=0; +1024 jh=1)

#define GLD16(G, L) __builtin_amdgcn_global_load_lds(                         \
    (const __attribute__((address_space(1))) void*)(G),                       \
    (__attribute__((address_space(3))) void*)(L), 16, 0, 0)
#define GLD4(G, L) __builtin_amdgcn_global_load_lds(                          \
    (const __attribute__((address_space(1))) void*)(G),                       \
    (__attribute__((address_space(3))) void*)(L), 4, 0, 0)

#define GATH(G, R0, R1) do {                                                  \
    _Pragma("unroll")                                                         \
    for (int e = 0; e < 4; ++e) {                                             \
      G[e]     = ebtl[h * 16 + R0[e]];                                        \
      G[4 + e] = ebtl[h * 16 + R1[e]];                                        \
    }                                                                         \
  } while (0)

#define COMP(K0, K1, V0, V1, G) do {                                          \
    f32x4 z = {};                                                             \
    f32x4 s0 = __builtin_amdgcn_mfma_f32_16x16x32_bf16(K0, qf, z, 0, 0, 0);   \
    f32x4 s1 = __builtin_amdgcn_mfma_f32_16x16x32_bf16(K1, qf, z, 0, 0, 0);   \
    bf16x8 pa;                                                                \
    _Pragma("unroll")                                                         \
    for (int e = 0; e < 4; ++e) {                                             \
      float p0 = __expf(s0[e]) * G[e];                                        \
      float p1 = __expf(s1[e]) * G[4 + e];                                    \
      l_acc += p0 + p1;                                                       \
      pa[e] = (bf16)p0;                                                       \
      pa[4 + e] = (bf16)p1;                                                   \
    }                                                                         \
    oacc[0] = __builtin_amdgcn_mfma_f32_16x16x32_bf16(pa, V0, oacc[0], 0, 0, 0); \
    oacc[1] = __builtin_amdgcn_mfma_f32_16x16x32_bf16(pa, V1, oacc[1], 0, 0, 0); \
  } while (0)

// One j-tile: DMA KV(T+1) into buf BN, rel(T+3) into buf BR3; counted wait;
// arrival barrier; read tile T (KV buf BC, rel-prefetch buf BRN); compute;
// free barrier.
#define TILE(TT, BC, BN, BRN, BR3, GC, GN) do {                               \
    int tn_ = ((TT) + 1) & 31, tr_ = ((TT) + 3) & 31;                         \
    GLD16(kTb + tn_ * 2048 + kc0,       KBp + (BN) * 16384 + h * 2048);       \
    GLD16(kTb + tn_ * 2048 + kc0 + 1024, KBp + (BN) * 16384 + h * 2048 + 1024);\
    GLD16(vTb + tn_ * 64 + vc0,         VBp + (BN) * 16384 + h * 2048);       \
    GLD16(vTb + tn_ * 64 + vc0 + 32768, VBp + (BN) * 16384 + h * 2048 + 1024);\
    GLD4(rb0 + tr_ * 128 + rc,          RBp + (BR3) * 2048 + h * 256);        \
    asm volatile("s_waitcnt vmcnt(6)" ::: "memory");                          \
    __builtin_amdgcn_s_barrier();                                             \
    bf16x8 kf0 = *(const bf16x8*)(KBp + (BC) * 16384 + kr);                   \
    bf16x8 kf1 = *(const bf16x8*)(KBp + (BC) * 16384 + kr + 1024);            \
    bf16x8 vf0 = *(const bf16x8*)(VBp + (BC) * 16384 + kr);                   \
    bf16x8 vf1 = *(const bf16x8*)(VBp + (BC) * 16384 + kr + 1024);            \
    i32x4 rv0 = *(const i32x4*)(RBp + (BRN) * 2048 + rr);                     \
    i32x4 rv1 = *(const i32x4*)(RBp + (BRN) * 2048 + rr + 1024);              \
    GATH(GN, rv0, rv1);                                                       \
    COMP(kf0, kf1, vf0, vf1, GC);                                             \
    __builtin_amdgcn_s_barrier();                                             \
  } while (0)

  f32x4 oacc[2] = {};
  float l_acc = 0.f;
  float gA[8], gB[8];

  // ---- prologue: KV(0) -> kvbuf0; rel(0,1,2) -> rbuf 0,1,2; gather gA(0).
  GLD16(kTb + kc0,        KBp + h * 2048);
  GLD16(kTb + kc0 + 1024, KBp + h * 2048 + 1024);
  GLD16(vTb + vc0,         VBp + h * 2048);
  GLD16(vTb + vc0 + 32768, VBp + h * 2048 + 1024);
  GLD4(rb0 + rc,       RBp + h * 256);
  GLD4(rb0 + 128 + rc, RBp + 2048 + h * 256);
  GLD4(rb0 + 256 + rc, RBp + 4096 + h * 256);
  asm volatile("s_waitcnt vmcnt(2)" ::: "memory");  // rel(0)+KV(0) arrived (own)
  __syncthreads();                                  // all waves' arrivals + ebtl
  {
    i32x4 rv0 = *(const i32x4*)(RBp + rr);
    i32x4 rv1 = *(const i32x4*)(RBp + rr + 1024);
    GATH(gA, rv0, rv1);
  }

#pragma unroll 1
  for (int t = 0; t < 32; t += 4) {
    TILE(t + 0, 0, 1, 1, 3, gA, gB);
    TILE(t + 1, 1, 0, 2, 0, gB, gA);
    TILE(t + 2, 0, 1, 3, 1, gA, gB);
    TILE(t + 3, 1, 0, 0, 2, gB, gA);
  }
#undef TILE
#undef COMP
#undef GATH
#undef GLD16
#undef GLD4

  // drain all DMAs (incl. wrapped tail issues) before aliasing smem as attL
  asm volatile("s_waitcnt vmcnt(0)" ::: "memory");
  __syncthreads();

  // row sums: lane's p's are all for q-row l16 -> reduce across quads.
  float lsum = l_acc;
  lsum += __shfl_xor(lsum, 16);
  lsum += __shfl_xor(lsum, 32);
  float inv = 1.f / lsum;   // inv for q-row = l16

  bf16 (*attL)[264] = (bf16(*)[264])(void*)smem;
#pragma unroll
  for (int r = 0; r < 4; ++r) {
    float invr = __shfl(inv, quad * 4 + r);
    attL[quad * 4 + r][h * 32 + l16] = (bf16)(oacc[0][r] * invr);
    attL[quad * 4 + r][h * 32 + 16 + l16] = (bf16)(oacc[1][r] * invr);
  }
  __syncthreads();

  // fused projection: wave h computes out[16 rows][h*32 .. h*32+31]
  f32x4 pacc[2] = {};
  const bf16* wp = Wp_tiled + ((h * 32 + l16) * 32 + quad * 8);  // + kt*8192, +512 for ni=1
#pragma unroll
  for (int kt = 0; kt < 8; ++kt) {
    bf16x8 afr = *reinterpret_cast<const bf16x8*>(&attL[l16][kt * 32 + quad * 8]);
    bf16x8 b0 = *reinterpret_cast<const bf16x8*>(wp + kt * 8192);
    bf16x8 b1 = *reinterpret_cast<const bf16x8*>(wp + kt * 8192 + 512);
    pacc[0] = __builtin_amdgcn_mfma_f32_16x16x32_bf16(afr, b0, pacc[0], 0, 0, 0);
    pacc[1] = __builtin_amdgcn_mfma_f32_16x16x32_bf16(afr, b1, pacc[1], 0, 0, 0);
  }
  float bi0 = bias[h * 32 + l16];
  float bi1 = bias[h * 32 + 16 + l16];
#pragma unroll
  for (int r = 0; r < 4; ++r) {
    long rowoff = (bN + i0 + quad * 4 + r) * C_ + h * 32;
    out[rowoff + l16] = pacc[0][r] + bi0;
    out[rowoff + 16 + l16] = pacc[1][r] + bi1;
  }
}

// ---------------------------------------------------------------------------
extern "C" void kernel_launch(void* const* d_in, const int* in_sizes, int n_in,
                              void* d_out, int out_size, void* d_ws, size_t ws_size,
                              hipStream_t stream) {
  const float* X     = (const float*)d_in[0];   // att_embedding [8,1024,256] fp32
  const int*   rel   = (const int*)d_in[1];     // relation_position [8,1024,1024]
  const int*   rlen  = (const int*)d_in[2];     // rel_len [8]
  const float* Wqkv  = (const float*)d_in[3];   // [256,768] fp32
  const float* Wproj = (const float*)d_in[4];   // [256,256] fp32
  const float* bproj = (const float*)d_in[5];   // [256] fp32
  const float* btab  = (const float*)d_in[6];   // [10,8] fp32
  float* out = (float*)d_out;                   // [8,1024,256] fp32

  char* ws = (char*)d_ws;
  bf16* Wq_tiled = (bf16*)ws;                            // 393216 B
  bf16* Wp_tiled = (bf16*)(ws + 393216);                 // 131072 B
  bf16* q  = (bf16*)(ws + 524288);                       // 4 MiB
  bf16* kT = (bf16*)(ws + 524288 + 4194304);             // 4 MiB
  bf16* vT = (bf16*)(ws + 524288 + 2 * 4194304);         // 4 MiB

  prep<<<dim3(1024), 256, 0, stream>>>(Wqkv, Wproj, Wq_tiled, Wp_tiled);
  gemm_qkv<<<dim3(8192 / 128, C3_ / 128), 256, 0, stream>>>(X, Wq_tiled, q, kT, vT);
  flash_attn<<<dim3(N_ / 16, B_), 512, 0, stream>>>(
      q, kT, vT, rel, rlen, btab, Wp_tiled, bproj, out);
}